// Round 5
// baseline (194.535 us; speedup 1.0000x reference)
//
#include <hip/hip_runtime.h>
#include <hip/hip_bf16.h>

// B=8, T=4096, C=384, H=64 causal single-head attention. fp32 in/out.
//
// Pipeline:
//   k1: Wt[3][64][384] = bf16(W^T)
//   k2: fused QKV projection (MFMA, bf16). q pre-scaled by C^-0.5*log2e,
//       k row-major, v transposed (vt[h][row]).
//   k3: flash attention: 512-thr blocks, 2 wave-groups split the k-tiles
//       (even/odd), K/V register-prefetched 1 iter ahead, online softmax.
// Round-5: LDS diet for 3 blocks/CU (was 2): P_lds stride 72->64 with XOR
// swizzle (s ^= (q&7)<<3; rows stay 16B aligned, b128 reads bank-uniform).
// KV(36864)+P(16384)=53248B -> 3x53248=159744 <= 163840. Plus ballot-gated
// O-rescale skip (max rarely updates in late tiles).

typedef __bf16 bf16x8 __attribute__((ext_vector_type(8)));
typedef float  f32x4  __attribute__((ext_vector_type(4)));

#define BB   8
#define TT   4096
#define CC   384
#define HH   64
#define NROW (BB*TT)       // 32768
// C^-0.5 * log2(e): fold softmax scale + exp2 conversion into q at projection
#define QSCALE (0.05103103630798288f * 1.4426950408889634f)

#if __has_builtin(__builtin_amdgcn_exp2f)
#define EXP2(x) __builtin_amdgcn_exp2f(x)
#else
#define EXP2(x) exp2f(x)
#endif

// Compiler memory fence + HW LDS drain: orders wave-local LDS write->read.
#define LDS_ROUNDTRIP_FENCE() __asm volatile("s_waitcnt lgkmcnt(0)" ::: "memory")

__device__ __forceinline__ unsigned short f2bf(float f) {
    __bf16 h = (__bf16)f;
    return __builtin_bit_cast(unsigned short, h);
}

// ---------------------------------------------------------------- kernel 1
// Wt[mat][h][c] = bf16(W[mat][c][h]), via LDS tile (coalesced both sides).
__global__ __launch_bounds__(256) void wtrans_kernel(
        const float* __restrict__ Wk,
        const float* __restrict__ Wq,
        const float* __restrict__ Wv,
        unsigned short* __restrict__ Wt) {
    __shared__ __align__(16) unsigned short tile[64][72];
    const float* Wm = (blockIdx.y == 0) ? Wk : ((blockIdx.y == 1) ? Wq : Wv);
    unsigned short* Wtm = Wt + blockIdx.y * (HH * CC);
    const int c0 = blockIdx.x * 64;
#pragma unroll
    for (int i = 0; i < 16; ++i) {
        int id = threadIdx.x + i * 256;         // 0..4095
        int c = id >> 6, h = id & 63;
        tile[c][h] = f2bf(Wm[(c0 + c) * HH + h]);   // coalesced read
    }
    __syncthreads();
#pragma unroll
    for (int i = 0; i < 16; ++i) {
        int id = threadIdx.x + i * 256;
        int h = id >> 6, c = id & 63;
        Wtm[h * CC + c0 + c] = tile[c][h];      // coalesced write
    }
}

// ---------------------------------------------------------------- kernel 2
// QKV projection: [32768,384]x[384,64] x3 with 16x16x32 bf16 MFMA.
// Block = 256 thr (4 waves), 64 rows/block, each wave 16 rows, N=64 (4 tiles).
__global__ __launch_bounds__(256) void qkv_kernel(
        const float* __restrict__ x,
        const unsigned short* __restrict__ Wt,     // [3][64][384] bf16
        unsigned short* __restrict__ q_ws,         // [32768][64], pre-scaled
        unsigned short* __restrict__ k_ws,         // [32768][64]
        unsigned short* __restrict__ vt_ws) {      // [64][32768]
    __shared__ __align__(16) unsigned short vtile[64][72];   // [h][row_local]

    const int lane = threadIdx.x & 63;
    const int wv   = threadIdx.x >> 6;
    const int l15  = lane & 15;
    const int quad = lane >> 4;
    const int rb   = blockIdx.x * 64;
    const int row  = rb + wv * 16 + l15;           // A-frag m index

    f32x4 acc[3][4];
    const f32x4 zero = {0.f, 0.f, 0.f, 0.f};
#pragma unroll
    for (int m = 0; m < 3; ++m)
#pragma unroll
        for (int nt = 0; nt < 4; ++nt) acc[m][nt] = zero;

    const float* xrow = x + (long)row * CC;
#pragma unroll
    for (int ch = 0; ch < 6; ++ch) {
#pragma unroll
        for (int kg = 0; kg < 2; ++kg) {
            const int coff = ch * 64 + kg * 32 + quad * 8;
            float4 u0 = *reinterpret_cast<const float4*>(xrow + coff);
            float4 u1 = *reinterpret_cast<const float4*>(xrow + coff + 4);
            bf16x8 a;
            a[0] = (__bf16)u0.x; a[1] = (__bf16)u0.y;
            a[2] = (__bf16)u0.z; a[3] = (__bf16)u0.w;
            a[4] = (__bf16)u1.x; a[5] = (__bf16)u1.y;
            a[6] = (__bf16)u1.z; a[7] = (__bf16)u1.w;
#pragma unroll
            for (int m = 0; m < 3; ++m) {
                const unsigned short* wtm = Wt + m * (HH * CC);
#pragma unroll
                for (int nt = 0; nt < 4; ++nt) {
                    bf16x8 bfr = *reinterpret_cast<const bf16x8*>(
                        wtm + (nt * 16 + l15) * CC + coff);
                    acc[m][nt] = __builtin_amdgcn_mfma_f32_16x16x32_bf16(
                        a, bfr, acc[m][nt], 0, 0, 0);
                }
            }
        }
    }

    // Epilogue. C-layout: value[m][nt][r] = out[row = quad*4+r (local)][h = nt*16+l15]
    const int rloc = wv * 16 + quad * 4;           // local row base
#pragma unroll
    for (int nt = 0; nt < 4; ++nt) {
        const int h = nt * 16 + l15;
#pragma unroll
        for (int r = 0; r < 4; ++r) {
            const int gr = rb + rloc + r;
            k_ws[gr * HH + h] = f2bf(acc[0][nt][r]);
            q_ws[gr * HH + h] = f2bf(acc[1][nt][r] * QSCALE);
            vtile[h][rloc + r] = f2bf(acc[2][nt][r]);
        }
    }
    __syncthreads();
    // vt_ws[h][rb..rb+64] <- vtile[h][0..64], coalesced 16B stores
#pragma unroll
    for (int i = 0; i < 2; ++i) {
        int id = threadIdx.x + i * 256;            // 0..511
        int h = id >> 3, seg = id & 7;
        *reinterpret_cast<uint4*>(&vt_ws[h * NROW + rb + seg * 8]) =
            *reinterpret_cast<const uint4*>(&vtile[h][seg * 8]);
    }
}

// ---------------------------------------------------------------- kernel 3
// Flash attention, split-K-in-block. 512 thr = 2 wave-groups x 4 waves.
// Group g handles k-tiles t = 2j+g; both groups share barriers (same count).
__global__ __launch_bounds__(512, 6) void attn_kernel(
        const unsigned short* __restrict__ q_ws,
        const unsigned short* __restrict__ k_ws,
        const unsigned short* __restrict__ vt_ws,
        float* __restrict__ out) {
    __shared__ __align__(16) unsigned short KV_lds[4 * 64 * 72]; // K0 V0 K1 V1
    // P: per-wave 16 rows x 64 s, stride 64, XOR-swizzled (s ^ (q&7)<<3).
    __shared__ __align__(16) unsigned short P_lds[8 * 16 * 64];

    const int lane = threadIdx.x & 63;
    const int wv8  = threadIdx.x >> 6;     // 0..7
    const int grp  = wv8 >> 2;             // wave-group 0/1
    const int wg   = wv8 & 3;              // wave within group
    const int g256 = threadIdx.x & 255;    // thread id within group
    const int l15  = lane & 15;
    const int quad = lane >> 4;

    const int bid = blockIdx.x;
    const int b   = bid & 7;
    const int qt  = (TT / 64 - 1) - (bid >> 3);    // longest blocks first
    const int qrow = qt * 64 + wg * 16 + l15;      // this lane's q column index

    unsigned short* Kb = KV_lds + grp * (2 * 64 * 72);
    unsigned short* Vb = Kb + 64 * 72;

    // Q fragments (B-operand: n=q=l15, k=d=quad*8+j), pre-scaled in q_ws
    const unsigned short* qbase = q_ws + (b * TT + qrow) * HH;
    const bf16x8 qf0 = *reinterpret_cast<const bf16x8*>(qbase + quad * 8);
    const bf16x8 qf1 = *reinterpret_cast<const bf16x8*>(qbase + 32 + quad * 8);

    const f32x4 zero = {0.f, 0.f, 0.f, 0.f};
    f32x4 o[4];
#pragma unroll
    for (int dt = 0; dt < 4; ++dt) o[dt] = zero;
    float mprev = -1e30f, lsum = 0.f;

    const int pbase = wv8 * 1024 + l15 * 64;       // this lane's P row base
    const int pxor  = (l15 & 7) << 3;              // bank swizzle

    // staging geometry: thread covers rows r0 and r0+32, 16B segment sg0
    const int r0  = g256 >> 3;
    const int sg0 = (g256 & 7) * 8;
    uint4 kreg0, kreg1, vreg0, vreg1;

#define ISSUE(t) do {                                                        \
        kreg0 = *reinterpret_cast<const uint4*>(                             \
            k_ws + (b * TT + (t) * 64 + r0) * HH + sg0);                     \
        kreg1 = *reinterpret_cast<const uint4*>(                             \
            k_ws + (b * TT + (t) * 64 + r0 + 32) * HH + sg0);                \
        vreg0 = *reinterpret_cast<const uint4*>(                             \
            vt_ws + r0 * NROW + b * TT + (t) * 64 + sg0);                    \
        vreg1 = *reinterpret_cast<const uint4*>(                             \
            vt_ws + (r0 + 32) * NROW + b * TT + (t) * 64 + sg0);             \
    } while (0)

    if (grp <= qt) ISSUE(grp);
    const int nIter = (qt + 2) >> 1;               // ceil((qt+1)/2)

    for (int j = 0; j < nIter; ++j) {
        const int t = 2 * j + grp;
        const bool act = (t <= qt);
        __syncthreads();                           // prior LDS reads done
        if (act) {
            *reinterpret_cast<uint4*>(Kb + r0 * 72 + sg0)        = kreg0;
            *reinterpret_cast<uint4*>(Kb + (r0 + 32) * 72 + sg0) = kreg1;
            *reinterpret_cast<uint4*>(Vb + r0 * 72 + sg0)        = vreg0;
            *reinterpret_cast<uint4*>(Vb + (r0 + 32) * 72 + sg0) = vreg1;
        }
        __syncthreads();
        const int tn = t + 2;                      // prefetch next tile
        if (tn <= qt) ISSUE(tn);
        if (!act) continue;

        const int s0 = t * 64;
        // S^T = K * Q^T : M=s(64 -> 4 tiles), N=q(16), K=d(64 -> 2 frags)
        f32x4 sc[4];
#pragma unroll
        for (int st = 0; st < 4; ++st) {
            const unsigned short* kr = Kb + (st * 16 + l15) * 72;
            bf16x8 ka0 = *reinterpret_cast<const bf16x8*>(kr + quad * 8);
            bf16x8 ka1 = *reinterpret_cast<const bf16x8*>(kr + 32 + quad * 8);
            f32x4 z = zero;
            z = __builtin_amdgcn_mfma_f32_16x16x32_bf16(ka0, qf0, z, 0, 0, 0);
            z = __builtin_amdgcn_mfma_f32_16x16x32_bf16(ka1, qf1, z, 0, 0, 0);
            sc[st] = z;
        }

        // causal mask (diagonal tile only): row = s = st*16+quad*4+r, col = q
        if (t == qt) {
#pragma unroll
            for (int st = 0; st < 4; ++st)
#pragma unroll
                for (int r = 0; r < 4; ++r) {
                    int sg = s0 + st * 16 + quad * 4 + r;
                    if (sg > qrow) sc[st][r] = -1e30f;
                }
        }

        // online softmax (scores already in log2 domain)
        float mloc = -1e30f;
#pragma unroll
        for (int st = 0; st < 4; ++st)
#pragma unroll
            for (int r = 0; r < 4; ++r) mloc = fmaxf(mloc, sc[st][r]);
        mloc = fmaxf(mloc, __shfl_xor(mloc, 16));
        mloc = fmaxf(mloc, __shfl_xor(mloc, 32));
        const float mnew = fmaxf(mprev, mloc);
        // max update is rare in late tiles: skip rescale when no row changed
        const unsigned long long anych = __ballot(mnew > mprev);
        float alpha = 1.0f;
        if (anych) alpha = EXP2(mprev - mnew);

        float psum = 0.f;
#pragma unroll
        for (int st = 0; st < 4; ++st) {
            union { unsigned short us[4]; uint2 u2; } pk;
#pragma unroll
            for (int r = 0; r < 4; ++r) {
                float p = EXP2(sc[st][r] - mnew);
                psum += p;
                pk.us[r] = f2bf(p);
            }
            *reinterpret_cast<uint2*>(
                &P_lds[pbase + ((st * 16 + quad * 4) ^ pxor)]) = pk.u2;
        }
        psum += __shfl_xor(psum, 16);
        psum += __shfl_xor(psum, 32);
        lsum = lsum * alpha + psum;
        mprev = mnew;

        if (anych) {
            // rescale O accumulator: O rows are q = quad*4+r
            float ar[4];
#pragma unroll
            for (int r = 0; r < 4; ++r) ar[r] = __shfl(alpha, quad * 4 + r);
#pragma unroll
            for (int dt = 0; dt < 4; ++dt)
#pragma unroll
                for (int r = 0; r < 4; ++r) o[dt][r] *= ar[r];
        }

        LDS_ROUNDTRIP_FENCE();   // wave-local P write->read ordering

        bf16x8 pf0 = *reinterpret_cast<const bf16x8*>(
            &P_lds[pbase + ((quad * 8) ^ pxor)]);
        bf16x8 pf1 = *reinterpret_cast<const bf16x8*>(
            &P_lds[pbase + ((32 + quad * 8) ^ pxor)]);
#pragma unroll
        for (int dt = 0; dt < 4; ++dt) {
            const unsigned short* vr = Vb + (dt * 16 + l15) * 72;
            bf16x8 vb0 = *reinterpret_cast<const bf16x8*>(vr + quad * 8);
            bf16x8 vb1 = *reinterpret_cast<const bf16x8*>(vr + 32 + quad * 8);
            o[dt] = __builtin_amdgcn_mfma_f32_16x16x32_bf16(pf0, vb0, o[dt], 0, 0, 0);
            o[dt] = __builtin_amdgcn_mfma_f32_16x16x32_bf16(pf1, vb1, o[dt], 0, 0, 0);
        }
    }
#undef ISSUE

    // ---- merge the two wave-groups (online-softmax combine) ----
    __syncthreads();                               // all loop LDS traffic done
    float* xchg = (float*)KV_lds;                  // [64][65] fp32, 16.6 KB
    float* mx1  = (float*)P_lds;                   // [64]
    float* lx1  = mx1 + 64;

    if (grp == 1) {
        if (quad == 0) { mx1[wg * 16 + l15] = mprev; lx1[wg * 16 + l15] = lsum; }
#pragma unroll
        for (int dt = 0; dt < 4; ++dt)
#pragma unroll
            for (int r = 0; r < 4; ++r)
                xchg[(wg * 16 + quad * 4 + r) * 65 + dt * 16 + l15] = o[dt][r];
    }
    __syncthreads();
    if (grp == 0) {
#pragma unroll
        for (int r = 0; r < 4; ++r) {
            const int row = wg * 16 + quad * 4 + r;
            const float m0r = __shfl(mprev, quad * 4 + r);
            const float l0r = __shfl(lsum,  quad * 4 + r);
            const float m1r = mx1[row];
            const float l1r = lx1[row];
            const float ms  = fmaxf(m0r, m1r);
            const float w0  = EXP2(m0r - ms);
            const float w1  = EXP2(m1r - ms);
            const float rden = 1.0f / (w0 * l0r + w1 * l1r);
            const long grow = (long)(b * TT + qt * 64 + row);
#pragma unroll
            for (int dt = 0; dt < 4; ++dt) {
                const float o1 = xchg[row * 65 + dt * 16 + l15];
                out[grow * HH + dt * 16 + l15] = (o[dt][r] * w0 + o1 * w1) * rden;
            }
        }
    }
}

// ---------------------------------------------------------------- launch
extern "C" void kernel_launch(void* const* d_in, const int* in_sizes, int n_in,
                              void* d_out, int out_size, void* d_ws, size_t ws_size,
                              hipStream_t stream) {
    const float* x  = (const float*)d_in[0];
    const float* Wk = (const float*)d_in[1];
    const float* Wq = (const float*)d_in[2];
    const float* Wv = (const float*)d_in[3];
    float* out = (float*)d_out;

    char* ws = (char*)d_ws;
    unsigned short* Wt    = (unsigned short*)(ws);                         // 147456 B
    unsigned short* q_ws  = (unsigned short*)(ws + 147456);                // 4 MiB
    unsigned short* k_ws  = (unsigned short*)(ws + 147456 + 4194304);      // 4 MiB
    unsigned short* vt_ws = (unsigned short*)(ws + 147456 + 2 * 4194304);  // 4 MiB

    wtrans_kernel<<<dim3(6, 3), 256, 0, stream>>>(Wk, Wq, Wv, Wt);
    qkv_kernel<<<NROW / 64, 256, 0, stream>>>(x, Wt, q_ws, k_ws, vt_ws);
    attn_kernel<<<(TT / 64) * BB, 512, 0, stream>>>(q_ws, k_ws, vt_ws, out);
}

// Round 6
// 179.544 us; speedup vs baseline: 1.0835x; 1.0835x over previous
//
#include <hip/hip_runtime.h>
#include <hip/hip_bf16.h>

// B=8, T=4096, C=384, H=64 causal single-head attention. fp32 in/out.
//
// Pipeline:
//   k1: Wt[3][64][384] = bf16(W^T)
//   k2: fused QKV projection, split-C across 2 wave-groups (512 thr):
//       group g accumulates c in [192g,192g+192), partials combined in LDS.
//   k3: flash attention: 512-thr blocks, 2 wave-groups split the k-tiles
//       (even/odd), K/V register-prefetched 1 iter ahead, online softmax.
//
// Round-6: attn launch_bounds back to (512,4) — round 5's (512,6) squeezed
// VGPR 52->40 and spilled to scratch (WRITE_SIZE 8.2->22.5 MB, FETCH 6.2->12.7,
// dur 61.8->79.6). HW reaches 3 blocks/CU on its own: VGPR 52 -> 8 waves/SIMD
// possible, LDS 53248*3 = 159744 <= 163840. qkv split-C doubles its waves/SIMD
// (2->4) at unchanged HBM traffic.

typedef __bf16 bf16x8 __attribute__((ext_vector_type(8)));
typedef float  f32x4  __attribute__((ext_vector_type(4)));

#define BB   8
#define TT   4096
#define CC   384
#define HH   64
#define NROW (BB*TT)       // 32768
// C^-0.5 * log2(e): fold softmax scale + exp2 conversion into q at projection
#define QSCALE (0.05103103630798288f * 1.4426950408889634f)

#if __has_builtin(__builtin_amdgcn_exp2f)
#define EXP2(x) __builtin_amdgcn_exp2f(x)
#else
#define EXP2(x) exp2f(x)
#endif

// Compiler memory fence + HW LDS drain: orders wave-local LDS write->read.
#define LDS_ROUNDTRIP_FENCE() __asm volatile("s_waitcnt lgkmcnt(0)" ::: "memory")

__device__ __forceinline__ unsigned short f2bf(float f) {
    __bf16 h = (__bf16)f;
    return __builtin_bit_cast(unsigned short, h);
}

// ---------------------------------------------------------------- kernel 1
// Wt[mat][h][c] = bf16(W[mat][c][h]), via LDS tile (coalesced both sides).
__global__ __launch_bounds__(256) void wtrans_kernel(
        const float* __restrict__ Wk,
        const float* __restrict__ Wq,
        const float* __restrict__ Wv,
        unsigned short* __restrict__ Wt) {
    __shared__ __align__(16) unsigned short tile[64][72];
    const float* Wm = (blockIdx.y == 0) ? Wk : ((blockIdx.y == 1) ? Wq : Wv);
    unsigned short* Wtm = Wt + blockIdx.y * (HH * CC);
    const int c0 = blockIdx.x * 64;
#pragma unroll
    for (int i = 0; i < 16; ++i) {
        int id = threadIdx.x + i * 256;         // 0..4095
        int c = id >> 6, h = id & 63;
        tile[c][h] = f2bf(Wm[(c0 + c) * HH + h]);   // coalesced read
    }
    __syncthreads();
#pragma unroll
    for (int i = 0; i < 16; ++i) {
        int id = threadIdx.x + i * 256;
        int h = id >> 6, c = id & 63;
        Wtm[h * CC + c0 + c] = tile[c][h];      // coalesced write
    }
}

// ---------------------------------------------------------------- kernel 2
// QKV projection: [32768,384]x[384,64] x3 with 16x16x32 bf16 MFMA.
// 512 thr = 2 wave-groups x 4 waves. Both groups cover the SAME 64 rows;
// group g accumulates the c in [192g, 192g+192). Partial sums combined in LDS.
__global__ __launch_bounds__(512) void qkv_kernel(
        const float* __restrict__ x,
        const unsigned short* __restrict__ Wt,     // [3][64][384] bf16
        unsigned short* __restrict__ q_ws,         // [32768][64], pre-scaled
        unsigned short* __restrict__ k_ws,         // [32768][64]
        unsigned short* __restrict__ vt_ws) {      // [64][32768]
    // per-lane 12 f32x4 partials, padded to 13 to spread banks: 256*13*16B
    __shared__ __align__(16) f32x4 xacc[256 * 13];              // 53248 B
    __shared__ __align__(16) unsigned short vtile[64][72];      //  9216 B

    const int lane = threadIdx.x & 63;
    const int wv8  = threadIdx.x >> 6;     // 0..7
    const int grp  = wv8 >> 2;             // wave-group 0/1
    const int wg   = wv8 & 3;              // wave within group
    const int g256 = threadIdx.x & 255;    // thread id within group
    const int l15  = lane & 15;
    const int quad = lane >> 4;
    const int rb   = blockIdx.x * 64;
    const int row  = rb + wg * 16 + l15;           // A-frag m index

    f32x4 acc[3][4];
    const f32x4 zero = {0.f, 0.f, 0.f, 0.f};
#pragma unroll
    for (int m = 0; m < 3; ++m)
#pragma unroll
        for (int nt = 0; nt < 4; ++nt) acc[m][nt] = zero;

    const float* xrow = x + (long)row * CC + grp * 192;
#pragma unroll
    for (int ch = 0; ch < 3; ++ch) {
#pragma unroll
        for (int kg = 0; kg < 2; ++kg) {
            const int coff = ch * 64 + kg * 32 + quad * 8;      // within group's 192
            float4 u0 = *reinterpret_cast<const float4*>(xrow + coff);
            float4 u1 = *reinterpret_cast<const float4*>(xrow + coff + 4);
            bf16x8 a;
            a[0] = (__bf16)u0.x; a[1] = (__bf16)u0.y;
            a[2] = (__bf16)u0.z; a[3] = (__bf16)u0.w;
            a[4] = (__bf16)u1.x; a[5] = (__bf16)u1.y;
            a[6] = (__bf16)u1.z; a[7] = (__bf16)u1.w;
            const int gcoff = grp * 192 + coff;
#pragma unroll
            for (int m = 0; m < 3; ++m) {
                const unsigned short* wtm = Wt + m * (HH * CC);
#pragma unroll
                for (int nt = 0; nt < 4; ++nt) {
                    bf16x8 bfr = *reinterpret_cast<const bf16x8*>(
                        wtm + (nt * 16 + l15) * CC + gcoff);
                    acc[m][nt] = __builtin_amdgcn_mfma_f32_16x16x32_bf16(
                        a, bfr, acc[m][nt], 0, 0, 0);
                }
            }
        }
    }

    // combine the two groups' partials through LDS
    const int cidx = g256 * 13;
    if (grp == 1) {
#pragma unroll
        for (int m = 0; m < 3; ++m)
#pragma unroll
            for (int nt = 0; nt < 4; ++nt)
                xacc[cidx + m * 4 + nt] = acc[m][nt];
    }
    __syncthreads();

    if (grp == 0) {
#pragma unroll
        for (int m = 0; m < 3; ++m)
#pragma unroll
            for (int nt = 0; nt < 4; ++nt)
                acc[m][nt] += xacc[cidx + m * 4 + nt];

        // Epilogue. C-layout: acc[m][nt][r] = out[local row quad*4+r][h = nt*16+l15]
        const int rloc = wg * 16 + quad * 4;       // local row base
#pragma unroll
        for (int nt = 0; nt < 4; ++nt) {
            const int h = nt * 16 + l15;
#pragma unroll
            for (int r = 0; r < 4; ++r) {
                const int gr = rb + rloc + r;
                k_ws[gr * HH + h] = f2bf(acc[0][nt][r]);
                q_ws[gr * HH + h] = f2bf(acc[1][nt][r] * QSCALE);
                vtile[h][rloc + r] = f2bf(acc[2][nt][r]);
            }
        }
    }
    __syncthreads();
    // vt_ws[h][rb..rb+64] <- vtile[h][0..64], coalesced 16B stores (512 thr)
    {
        int id = threadIdx.x;                      // 0..511
        int h = id >> 3, seg = id & 7;
        *reinterpret_cast<uint4*>(&vt_ws[h * NROW + rb + seg * 8]) =
            *reinterpret_cast<const uint4*>(&vtile[h][seg * 8]);
    }
}

// ---------------------------------------------------------------- kernel 3
// Flash attention, split-K-in-block. 512 thr = 2 wave-groups x 4 waves.
// Group g handles k-tiles t = 2j+g; both groups share barriers (same count).
__global__ __launch_bounds__(512, 4) void attn_kernel(
        const unsigned short* __restrict__ q_ws,
        const unsigned short* __restrict__ k_ws,
        const unsigned short* __restrict__ vt_ws,
        float* __restrict__ out) {
    __shared__ __align__(16) unsigned short KV_lds[4 * 64 * 72]; // K0 V0 K1 V1
    // P: per-wave 16 rows x 64 s, stride 64, XOR-swizzled (s ^ (q&7)<<3).
    __shared__ __align__(16) unsigned short P_lds[8 * 16 * 64];

    const int lane = threadIdx.x & 63;
    const int wv8  = threadIdx.x >> 6;     // 0..7
    const int grp  = wv8 >> 2;             // wave-group 0/1
    const int wg   = wv8 & 3;              // wave within group
    const int g256 = threadIdx.x & 255;    // thread id within group
    const int l15  = lane & 15;
    const int quad = lane >> 4;

    const int bid = blockIdx.x;
    const int b   = bid & 7;
    const int qt  = (TT / 64 - 1) - (bid >> 3);    // longest blocks first
    const int qrow = qt * 64 + wg * 16 + l15;      // this lane's q column index

    unsigned short* Kb = KV_lds + grp * (2 * 64 * 72);
    unsigned short* Vb = Kb + 64 * 72;

    // Q fragments (B-operand: n=q=l15, k=d=quad*8+j), pre-scaled in q_ws
    const unsigned short* qbase = q_ws + (b * TT + qrow) * HH;
    const bf16x8 qf0 = *reinterpret_cast<const bf16x8*>(qbase + quad * 8);
    const bf16x8 qf1 = *reinterpret_cast<const bf16x8*>(qbase + 32 + quad * 8);

    const f32x4 zero = {0.f, 0.f, 0.f, 0.f};
    f32x4 o[4];
#pragma unroll
    for (int dt = 0; dt < 4; ++dt) o[dt] = zero;
    float mprev = -1e30f, lsum = 0.f;

    const int pbase = wv8 * 1024 + l15 * 64;       // this lane's P row base
    const int pxor  = (l15 & 7) << 3;              // bank swizzle

    // staging geometry: thread covers rows r0 and r0+32, 16B segment sg0
    const int r0  = g256 >> 3;
    const int sg0 = (g256 & 7) * 8;
    uint4 kreg0, kreg1, vreg0, vreg1;

#define ISSUE(t) do {                                                        \
        kreg0 = *reinterpret_cast<const uint4*>(                             \
            k_ws + (b * TT + (t) * 64 + r0) * HH + sg0);                     \
        kreg1 = *reinterpret_cast<const uint4*>(                             \
            k_ws + (b * TT + (t) * 64 + r0 + 32) * HH + sg0);                \
        vreg0 = *reinterpret_cast<const uint4*>(                             \
            vt_ws + r0 * NROW + b * TT + (t) * 64 + sg0);                    \
        vreg1 = *reinterpret_cast<const uint4*>(                             \
            vt_ws + (r0 + 32) * NROW + b * TT + (t) * 64 + sg0);             \
    } while (0)

    if (grp <= qt) ISSUE(grp);
    const int nIter = (qt + 2) >> 1;               // ceil((qt+1)/2)

    for (int j = 0; j < nIter; ++j) {
        const int t = 2 * j + grp;
        const bool act = (t <= qt);
        __syncthreads();                           // prior LDS reads done
        if (act) {
            *reinterpret_cast<uint4*>(Kb + r0 * 72 + sg0)        = kreg0;
            *reinterpret_cast<uint4*>(Kb + (r0 + 32) * 72 + sg0) = kreg1;
            *reinterpret_cast<uint4*>(Vb + r0 * 72 + sg0)        = vreg0;
            *reinterpret_cast<uint4*>(Vb + (r0 + 32) * 72 + sg0) = vreg1;
        }
        __syncthreads();
        const int tn = t + 2;                      // prefetch next tile
        if (tn <= qt) ISSUE(tn);
        if (!act) continue;

        const int s0 = t * 64;
        // S^T = K * Q^T : M=s(64 -> 4 tiles), N=q(16), K=d(64 -> 2 frags)
        f32x4 sc[4];
#pragma unroll
        for (int st = 0; st < 4; ++st) {
            const unsigned short* kr = Kb + (st * 16 + l15) * 72;
            bf16x8 ka0 = *reinterpret_cast<const bf16x8*>(kr + quad * 8);
            bf16x8 ka1 = *reinterpret_cast<const bf16x8*>(kr + 32 + quad * 8);
            f32x4 z = zero;
            z = __builtin_amdgcn_mfma_f32_16x16x32_bf16(ka0, qf0, z, 0, 0, 0);
            z = __builtin_amdgcn_mfma_f32_16x16x32_bf16(ka1, qf1, z, 0, 0, 0);
            sc[st] = z;
        }

        // causal mask (diagonal tile only): row = s = st*16+quad*4+r, col = q
        if (t == qt) {
#pragma unroll
            for (int st = 0; st < 4; ++st)
#pragma unroll
                for (int r = 0; r < 4; ++r) {
                    int sg = s0 + st * 16 + quad * 4 + r;
                    if (sg > qrow) sc[st][r] = -1e30f;
                }
        }

        // online softmax (scores already in log2 domain)
        float mloc = -1e30f;
#pragma unroll
        for (int st = 0; st < 4; ++st)
#pragma unroll
            for (int r = 0; r < 4; ++r) mloc = fmaxf(mloc, sc[st][r]);
        mloc = fmaxf(mloc, __shfl_xor(mloc, 16));
        mloc = fmaxf(mloc, __shfl_xor(mloc, 32));
        const float mnew = fmaxf(mprev, mloc);
        // max update is rare in late tiles: skip rescale when no row changed
        const unsigned long long anych = __ballot(mnew > mprev);
        float alpha = 1.0f;
        if (anych) alpha = EXP2(mprev - mnew);

        float psum = 0.f;
#pragma unroll
        for (int st = 0; st < 4; ++st) {
            union { unsigned short us[4]; uint2 u2; } pk;
#pragma unroll
            for (int r = 0; r < 4; ++r) {
                float p = EXP2(sc[st][r] - mnew);
                psum += p;
                pk.us[r] = f2bf(p);
            }
            *reinterpret_cast<uint2*>(
                &P_lds[pbase + ((st * 16 + quad * 4) ^ pxor)]) = pk.u2;
        }
        psum += __shfl_xor(psum, 16);
        psum += __shfl_xor(psum, 32);
        lsum = lsum * alpha + psum;
        mprev = mnew;

        if (anych) {
            // rescale O accumulator: O rows are q = quad*4+r
            float ar[4];
#pragma unroll
            for (int r = 0; r < 4; ++r) ar[r] = __shfl(alpha, quad * 4 + r);
#pragma unroll
            for (int dt = 0; dt < 4; ++dt)
#pragma unroll
                for (int r = 0; r < 4; ++r) o[dt][r] *= ar[r];
        }

        LDS_ROUNDTRIP_FENCE();   // wave-local P write->read ordering

        bf16x8 pf0 = *reinterpret_cast<const bf16x8*>(
            &P_lds[pbase + ((quad * 8) ^ pxor)]);
        bf16x8 pf1 = *reinterpret_cast<const bf16x8*>(
            &P_lds[pbase + ((32 + quad * 8) ^ pxor)]);
#pragma unroll
        for (int dt = 0; dt < 4; ++dt) {
            const unsigned short* vr = Vb + (dt * 16 + l15) * 72;
            bf16x8 vb0 = *reinterpret_cast<const bf16x8*>(vr + quad * 8);
            bf16x8 vb1 = *reinterpret_cast<const bf16x8*>(vr + 32 + quad * 8);
            o[dt] = __builtin_amdgcn_mfma_f32_16x16x32_bf16(pf0, vb0, o[dt], 0, 0, 0);
            o[dt] = __builtin_amdgcn_mfma_f32_16x16x32_bf16(pf1, vb1, o[dt], 0, 0, 0);
        }
    }
#undef ISSUE

    // ---- merge the two wave-groups (online-softmax combine) ----
    __syncthreads();                               // all loop LDS traffic done
    float* xchg = (float*)KV_lds;                  // [64][65] fp32, 16.6 KB
    float* mx1  = (float*)P_lds;                   // [64]
    float* lx1  = mx1 + 64;

    if (grp == 1) {
        if (quad == 0) { mx1[wg * 16 + l15] = mprev; lx1[wg * 16 + l15] = lsum; }
#pragma unroll
        for (int dt = 0; dt < 4; ++dt)
#pragma unroll
            for (int r = 0; r < 4; ++r)
                xchg[(wg * 16 + quad * 4 + r) * 65 + dt * 16 + l15] = o[dt][r];
    }
    __syncthreads();
    if (grp == 0) {
#pragma unroll
        for (int r = 0; r < 4; ++r) {
            const int row = wg * 16 + quad * 4 + r;
            const float m0r = __shfl(mprev, quad * 4 + r);
            const float l0r = __shfl(lsum,  quad * 4 + r);
            const float m1r = mx1[row];
            const float l1r = lx1[row];
            const float ms  = fmaxf(m0r, m1r);
            const float w0  = EXP2(m0r - ms);
            const float w1  = EXP2(m1r - ms);
            const float rden = 1.0f / (w0 * l0r + w1 * l1r);
            const long grow = (long)(b * TT + qt * 64 + row);
#pragma unroll
            for (int dt = 0; dt < 4; ++dt) {
                const float o1 = xchg[row * 65 + dt * 16 + l15];
                out[grow * HH + dt * 16 + l15] = (o[dt][r] * w0 + o1 * w1) * rden;
            }
        }
    }
}

// ---------------------------------------------------------------- launch
extern "C" void kernel_launch(void* const* d_in, const int* in_sizes, int n_in,
                              void* d_out, int out_size, void* d_ws, size_t ws_size,
                              hipStream_t stream) {
    const float* x  = (const float*)d_in[0];
    const float* Wk = (const float*)d_in[1];
    const float* Wq = (const float*)d_in[2];
    const float* Wv = (const float*)d_in[3];
    float* out = (float*)d_out;

    char* ws = (char*)d_ws;
    unsigned short* Wt    = (unsigned short*)(ws);                         // 147456 B
    unsigned short* q_ws  = (unsigned short*)(ws + 147456);                // 4 MiB
    unsigned short* k_ws  = (unsigned short*)(ws + 147456 + 4194304);      // 4 MiB
    unsigned short* vt_ws = (unsigned short*)(ws + 147456 + 2 * 4194304);  // 4 MiB

    wtrans_kernel<<<dim3(6, 3), 256, 0, stream>>>(Wk, Wq, Wv, Wt);
    qkv_kernel<<<NROW / 64, 512, 0, stream>>>(x, Wt, q_ws, k_ws, vt_ws);
    attn_kernel<<<(TT / 64) * BB, 512, 0, stream>>>(q_ws, k_ws, vt_ws, out);
}

// Round 7
// 174.120 us; speedup vs baseline: 1.1172x; 1.0311x over previous
//
#include <hip/hip_runtime.h>
#include <hip/hip_bf16.h>

// B=8, T=4096, C=384, H=64 causal single-head attention. fp32 in/out.
//
// Round-7: BARRIER-FREE attention. k_ws and vt_ws are stored in MFMA
// fragment order, so each wave loads A/B fragments directly from global as
// fully-coalesced 1KB wave-loads (no LDS staging, no __syncthreads in the
// k-loop). All 16 waves/CU run independently; L1 serves intra-group reuse,
// per-XCD L2 holds one batch's KV (2MB<4MB, b=bid&7 placement heuristic).
//
//  k_frag layout: [rt=row/16][c8=col/8][i=row%16][j=col%8]   (bf16)
//  vt_frag layout: [st=row/64][dt=d/16][sc=s%64/8][i=d%16][j=s%8]

typedef __bf16 bf16x8 __attribute__((ext_vector_type(8)));
typedef float  f32x4  __attribute__((ext_vector_type(4)));

#define BB   8
#define TT   4096
#define CC   384
#define HH   64
#define NROW (BB*TT)       // 32768
// C^-0.5 * log2(e): fold softmax scale + exp2 conversion into q at projection
#define QSCALE (0.05103103630798288f * 1.4426950408889634f)

#if __has_builtin(__builtin_amdgcn_exp2f)
#define EXP2(x) __builtin_amdgcn_exp2f(x)
#else
#define EXP2(x) exp2f(x)
#endif

// Compiler memory fence + HW LDS drain: orders wave-local LDS write->read.
#define LDS_ROUNDTRIP_FENCE() __asm volatile("s_waitcnt lgkmcnt(0)" ::: "memory")

__device__ __forceinline__ unsigned short f2bf(float f) {
    __bf16 h = (__bf16)f;
    return __builtin_bit_cast(unsigned short, h);
}

// ---------------------------------------------------------------- kernel 1
// Wt[mat][h][c] = bf16(W[mat][c][h]), via LDS tile (coalesced both sides).
__global__ __launch_bounds__(256) void wtrans_kernel(
        const float* __restrict__ Wk,
        const float* __restrict__ Wq,
        const float* __restrict__ Wv,
        unsigned short* __restrict__ Wt) {
    __shared__ __align__(16) unsigned short tile[64][72];
    const float* Wm = (blockIdx.y == 0) ? Wk : ((blockIdx.y == 1) ? Wq : Wv);
    unsigned short* Wtm = Wt + blockIdx.y * (HH * CC);
    const int c0 = blockIdx.x * 64;
#pragma unroll
    for (int i = 0; i < 16; ++i) {
        int id = threadIdx.x + i * 256;         // 0..4095
        int c = id >> 6, h = id & 63;
        tile[c][h] = f2bf(Wm[(c0 + c) * HH + h]);   // coalesced read
    }
    __syncthreads();
#pragma unroll
    for (int i = 0; i < 16; ++i) {
        int id = threadIdx.x + i * 256;
        int h = id >> 6, c = id & 63;
        Wtm[h * CC + c0 + c] = tile[c][h];      // coalesced write
    }
}

// ---------------------------------------------------------------- kernel 2
// QKV projection: [32768,384]x[384,64] x3 with 16x16x32 bf16 MFMA.
// 512 thr = 2 wave-groups x 4 waves; group g accumulates c in [192g,192g+192),
// partials combined in LDS. k and vt written in MFMA fragment layouts.
__global__ __launch_bounds__(512) void qkv_kernel(
        const float* __restrict__ x,
        const unsigned short* __restrict__ Wt,     // [3][64][384] bf16
        unsigned short* __restrict__ q_ws,         // [32768][64] row-major, pre-scaled
        unsigned short* __restrict__ k_ws,         // fragment layout
        unsigned short* __restrict__ vt_ws) {      // fragment layout
    __shared__ __align__(16) f32x4 xacc[256 * 13];              // 53248 B
    __shared__ __align__(16) unsigned short vtile[64][72];      //  9216 B

    const int lane = threadIdx.x & 63;
    const int wv8  = threadIdx.x >> 6;     // 0..7
    const int grp  = wv8 >> 2;             // wave-group 0/1
    const int wg   = wv8 & 3;              // wave within group
    const int g256 = threadIdx.x & 255;    // thread id within group
    const int l15  = lane & 15;
    const int quad = lane >> 4;
    const int rb   = blockIdx.x * 64;
    const int row  = rb + wg * 16 + l15;           // A-frag m index

    f32x4 acc[3][4];
    const f32x4 zero = {0.f, 0.f, 0.f, 0.f};
#pragma unroll
    for (int m = 0; m < 3; ++m)
#pragma unroll
        for (int nt = 0; nt < 4; ++nt) acc[m][nt] = zero;

    const float* xrow = x + (long)row * CC + grp * 192;
#pragma unroll
    for (int ch = 0; ch < 3; ++ch) {
#pragma unroll
        for (int kg = 0; kg < 2; ++kg) {
            const int coff = ch * 64 + kg * 32 + quad * 8;      // within group's 192
            float4 u0 = *reinterpret_cast<const float4*>(xrow + coff);
            float4 u1 = *reinterpret_cast<const float4*>(xrow + coff + 4);
            bf16x8 a;
            a[0] = (__bf16)u0.x; a[1] = (__bf16)u0.y;
            a[2] = (__bf16)u0.z; a[3] = (__bf16)u0.w;
            a[4] = (__bf16)u1.x; a[5] = (__bf16)u1.y;
            a[6] = (__bf16)u1.z; a[7] = (__bf16)u1.w;
            const int gcoff = grp * 192 + coff;
#pragma unroll
            for (int m = 0; m < 3; ++m) {
                const unsigned short* wtm = Wt + m * (HH * CC);
#pragma unroll
                for (int nt = 0; nt < 4; ++nt) {
                    bf16x8 bfr = *reinterpret_cast<const bf16x8*>(
                        wtm + (nt * 16 + l15) * CC + gcoff);
                    acc[m][nt] = __builtin_amdgcn_mfma_f32_16x16x32_bf16(
                        a, bfr, acc[m][nt], 0, 0, 0);
                }
            }
        }
    }

    // combine the two groups' partials through LDS
    const int cidx = g256 * 13;
    if (grp == 1) {
#pragma unroll
        for (int m = 0; m < 3; ++m)
#pragma unroll
            for (int nt = 0; nt < 4; ++nt)
                xacc[cidx + m * 4 + nt] = acc[m][nt];
    }
    __syncthreads();

    if (grp == 0) {
#pragma unroll
        for (int m = 0; m < 3; ++m)
#pragma unroll
            for (int nt = 0; nt < 4; ++nt)
                acc[m][nt] += xacc[cidx + m * 4 + nt];

        // Epilogue. C-layout: acc[m][nt][r] = out[local row quad*4+r][h = nt*16+l15]
        const int rt = (rb >> 4) + wg;             // global 16-row tile index
#pragma unroll
        for (int nt = 0; nt < 4; ++nt) {
            const int h  = nt * 16 + l15;
            const int c8 = h >> 3;
            const int jj = h & 7;
#pragma unroll
            for (int r = 0; r < 4; ++r) {
                const int gr = rb + wg * 16 + quad * 4 + r;
                const int ii = quad * 4 + r;       // row within 16-tile
                k_ws[((rt * 8 + c8) * 16 + ii) * 8 + jj] = f2bf(acc[0][nt][r]);
                q_ws[gr * HH + h] = f2bf(acc[1][nt][r] * QSCALE);
                vtile[h][ii + wg * 16] = f2bf(acc[2][nt][r]);
            }
        }
    }
    __syncthreads();
    // vt fragment store: chunk id = (dt*8+sc)*16+ii, perfectly coalesced.
    {
        int id = threadIdx.x;                      // 0..511
        int dt = id >> 7, sc = (id >> 4) & 7, ii = id & 15;
        unsigned short* dst = vt_ws + (long)(rb >> 6) * 4096
                              + (dt * 8 + sc) * 128 + ii * 8;
        *reinterpret_cast<uint4*>(dst) =
            *reinterpret_cast<const uint4*>(&vtile[dt * 16 + ii][sc * 8]);
    }
}

// ---------------------------------------------------------------- kernel 3
// Flash attention, barrier-free k-loop. 512 thr = 2 wave-groups x 4 waves;
// group g handles k-tiles t = 2j+g independently; merge via LDS at the end.
__global__ __launch_bounds__(512, 4) void attn_kernel(
        const unsigned short* __restrict__ q_ws,
        const unsigned short* __restrict__ k_ws,   // fragment layout
        const unsigned short* __restrict__ vt_ws,  // fragment layout
        float* __restrict__ out) {
    // P: per-wave 16 rows x 64 s, stride 64, XOR-swizzled (s ^ (q&7)<<3).
    __shared__ __align__(16) unsigned short P_lds[8 * 16 * 64];  // 16384 B
    __shared__ __align__(16) float xchg[64 * 65];                // 16640 B
    __shared__ float mx1[64], lx1[64];

    const int lane = threadIdx.x & 63;
    const int wv8  = threadIdx.x >> 6;     // 0..7
    const int grp  = wv8 >> 2;             // wave-group 0/1
    const int wg   = wv8 & 3;              // wave within group
    const int l15  = lane & 15;
    const int quad = lane >> 4;

    const int bid = blockIdx.x;
    const int b   = bid & 7;               // aligns b with XCD (round-robin)
    const int qt  = (TT / 64 - 1) - (bid >> 3);    // longest blocks first
    const int qrow = qt * 64 + wg * 16 + l15;      // this lane's q column index

    // Q fragments (B-operand: n=q=l15, k=d=quad*8+j), pre-scaled in q_ws
    const unsigned short* qbase = q_ws + (b * TT + qrow) * HH;
    const bf16x8 qf0 = *reinterpret_cast<const bf16x8*>(qbase + quad * 8);
    const bf16x8 qf1 = *reinterpret_cast<const bf16x8*>(qbase + 32 + quad * 8);

    const f32x4 zero = {0.f, 0.f, 0.f, 0.f};
    f32x4 o[4];
#pragma unroll
    for (int dt = 0; dt < 4; ++dt) o[dt] = zero;
    float mprev = -1e30f, lsum = 0.f;

    const int pbase = wv8 * 1024 + l15 * 64;       // this lane's P row base
    const int pxor  = (l15 & 7) << 3;              // bank swizzle

    for (int t = grp; t <= qt; t += 2) {
        const int s0 = t * 64;
        const unsigned short* ktile = k_ws + ((long)((b * TT + s0) >> 4)) * 1024;
        const unsigned short* vtile = vt_ws + ((long)((b * TT + s0) >> 6)) * 4096;

        // K A-frags: lane reads rows s=st*16+l15, cols quad*8.. — coalesced 1KB/load
        bf16x8 ka0[4], ka1[4];
#pragma unroll
        for (int st = 0; st < 4; ++st) {
            ka0[st] = *reinterpret_cast<const bf16x8*>(
                ktile + ((st * 8 + quad) * 16 + l15) * 8);
            ka1[st] = *reinterpret_cast<const bf16x8*>(
                ktile + ((st * 8 + 4 + quad) * 16 + l15) * 8);
        }
        // V B-frags: lane reads d=dt*16+l15, s=quad*8.. / 32+quad*8..
        bf16x8 vb0[4], vb1[4];
#pragma unroll
        for (int dt = 0; dt < 4; ++dt) {
            vb0[dt] = *reinterpret_cast<const bf16x8*>(
                vtile + dt * 1024 + quad * 128 + l15 * 8);
            vb1[dt] = *reinterpret_cast<const bf16x8*>(
                vtile + dt * 1024 + (4 + quad) * 128 + l15 * 8);
        }

        // S^T = K * Q^T : M=s(64 -> 4 tiles), N=q(16), K=d(64 -> 2 frags)
        f32x4 sc[4];
#pragma unroll
        for (int st = 0; st < 4; ++st) {
            f32x4 z = zero;
            z = __builtin_amdgcn_mfma_f32_16x16x32_bf16(ka0[st], qf0, z, 0, 0, 0);
            z = __builtin_amdgcn_mfma_f32_16x16x32_bf16(ka1[st], qf1, z, 0, 0, 0);
            sc[st] = z;
        }

        // causal mask (diagonal tile only): row = s = st*16+quad*4+r, col = q
        if (t == qt) {
#pragma unroll
            for (int st = 0; st < 4; ++st)
#pragma unroll
                for (int r = 0; r < 4; ++r) {
                    int sg = s0 + st * 16 + quad * 4 + r;
                    if (sg > qrow) sc[st][r] = -1e30f;
                }
        }

        // online softmax (scores already in log2 domain)
        float mloc = -1e30f;
#pragma unroll
        for (int st = 0; st < 4; ++st)
#pragma unroll
            for (int r = 0; r < 4; ++r) mloc = fmaxf(mloc, sc[st][r]);
        mloc = fmaxf(mloc, __shfl_xor(mloc, 16));
        mloc = fmaxf(mloc, __shfl_xor(mloc, 32));
        const float mnew = fmaxf(mprev, mloc);
        // max update is rare in late tiles: skip rescale when no row changed
        const unsigned long long anych = __ballot(mnew > mprev);
        float alpha = 1.0f;
        if (anych) alpha = EXP2(mprev - mnew);

        float psum = 0.f;
#pragma unroll
        for (int st = 0; st < 4; ++st) {
            union { unsigned short us[4]; uint2 u2; } pk;
#pragma unroll
            for (int r = 0; r < 4; ++r) {
                float p = EXP2(sc[st][r] - mnew);
                psum += p;
                pk.us[r] = f2bf(p);
            }
            *reinterpret_cast<uint2*>(
                &P_lds[pbase + ((st * 16 + quad * 4) ^ pxor)]) = pk.u2;
        }
        psum += __shfl_xor(psum, 16);
        psum += __shfl_xor(psum, 32);
        lsum = lsum * alpha + psum;
        mprev = mnew;

        if (anych) {
            // rescale O accumulator: O rows are q = quad*4+r
            float ar[4];
#pragma unroll
            for (int r = 0; r < 4; ++r) ar[r] = __shfl(alpha, quad * 4 + r);
#pragma unroll
            for (int dt = 0; dt < 4; ++dt)
#pragma unroll
                for (int r = 0; r < 4; ++r) o[dt][r] *= ar[r];
        }

        LDS_ROUNDTRIP_FENCE();   // wave-local P write->read ordering

        bf16x8 pf0 = *reinterpret_cast<const bf16x8*>(
            &P_lds[pbase + ((quad * 8) ^ pxor)]);
        bf16x8 pf1 = *reinterpret_cast<const bf16x8*>(
            &P_lds[pbase + ((32 + quad * 8) ^ pxor)]);
#pragma unroll
        for (int dt = 0; dt < 4; ++dt) {
            o[dt] = __builtin_amdgcn_mfma_f32_16x16x32_bf16(pf0, vb0[dt], o[dt], 0, 0, 0);
            o[dt] = __builtin_amdgcn_mfma_f32_16x16x32_bf16(pf1, vb1[dt], o[dt], 0, 0, 0);
        }
    }

    // ---- merge the two wave-groups (online-softmax combine) ----
    __syncthreads();
    if (grp == 1) {
        if (quad == 0) { mx1[wg * 16 + l15] = mprev; lx1[wg * 16 + l15] = lsum; }
#pragma unroll
        for (int dt = 0; dt < 4; ++dt)
#pragma unroll
            for (int r = 0; r < 4; ++r)
                xchg[(wg * 16 + quad * 4 + r) * 65 + dt * 16 + l15] = o[dt][r];
    }
    __syncthreads();
    if (grp == 0) {
#pragma unroll
        for (int r = 0; r < 4; ++r) {
            const int row = wg * 16 + quad * 4 + r;
            const float m0r = __shfl(mprev, quad * 4 + r);
            const float l0r = __shfl(lsum,  quad * 4 + r);
            const float m1r = mx1[row];
            const float l1r = lx1[row];
            const float ms  = fmaxf(m0r, m1r);
            const float w0  = EXP2(m0r - ms);
            const float w1  = EXP2(m1r - ms);
            const float rden = 1.0f / (w0 * l0r + w1 * l1r);
            const long grow = (long)(b * TT + qt * 64 + row);
#pragma unroll
            for (int dt = 0; dt < 4; ++dt) {
                const float o1 = xchg[row * 65 + dt * 16 + l15];
                out[grow * HH + dt * 16 + l15] = (o[dt][r] * w0 + o1 * w1) * rden;
            }
        }
    }
}

// ---------------------------------------------------------------- launch
extern "C" void kernel_launch(void* const* d_in, const int* in_sizes, int n_in,
                              void* d_out, int out_size, void* d_ws, size_t ws_size,
                              hipStream_t stream) {
    const float* x  = (const float*)d_in[0];
    const float* Wk = (const float*)d_in[1];
    const float* Wq = (const float*)d_in[2];
    const float* Wv = (const float*)d_in[3];
    float* out = (float*)d_out;

    char* ws = (char*)d_ws;
    unsigned short* Wt    = (unsigned short*)(ws);                         // 147456 B
    unsigned short* q_ws  = (unsigned short*)(ws + 147456);                // 4 MiB
    unsigned short* k_ws  = (unsigned short*)(ws + 147456 + 4194304);      // 4 MiB
    unsigned short* vt_ws = (unsigned short*)(ws + 147456 + 2 * 4194304);  // 4 MiB

    wtrans_kernel<<<dim3(6, 3), 256, 0, stream>>>(Wk, Wq, Wv, Wt);
    qkv_kernel<<<NROW / 64, 512, 0, stream>>>(x, Wt, q_ws, k_ws, vt_ws);
    attn_kernel<<<(TT / 64) * BB, 512, 0, stream>>>(q_ws, k_ws, vt_ws, out);
}